// Round 1
// 293.588 us; speedup vs baseline: 1.1240x; 1.1240x over previous
//
#include <hip/hip_runtime.h>
#include <cfloat>
#include <cstdint>

// Problem constants (reference: B=32, C=256, H=W=64, nh=4, hid=C/4=64, S=40)
#define B_    32
#define C_    256
#define HW_   4096
#define NH_   4
#define HID_  64
#define SSEL_ 40
#define GADD_ 0.0075f   // 0.3 * (1/40): pixel_imp collapses to 1/S exactly

using half8_t = __attribute__((ext_vector_type(8))) _Float16;
using half4_t = __attribute__((ext_vector_type(4))) _Float16;
using f32x4_t = __attribute__((ext_vector_type(4))) float;

// ---------------------------------------------------------------------------
// K1 v3: fp16 MFMA formulation of the graph_modulator MLP.
//   H1[64][px] = relu(W1 @ X + b1)  via v_mfma_f32_16x16x32_f16
//   m = 0.175 * sum_h sigmoid(W2 @ H1 + b2)   (layer 2 in-register)
// v2 post-mortem: MfmaUtil=0, VALUBusy=52%, 98.7us — a VALU fp32 GEMM at
// ~28% of vector peak. This version puts layer 1 on the matrix pipe
// (fp16 ingest, fp32 accumulate; error ~1e-4 in m, well under tolerance)
// and becomes HBM-bound on the single fp32 read of x (~21us floor).
//
// Block: 256 threads (4 waves), tile = 64 hid x 256 px, K = 256 in 4 chunks.
// LDS: WHu = W1 as fp16 [hid][256], XOR-swizzled (col^=(hid&7)<<2 dwords) —
//      conflict-free ds_read_b128 A-fragments.  32 KB
//      XTu = X chunk as fp16 [px][64ch], same swizzle on (px&7) — thread=px
//      gives coalesced dword global reads AND contiguous b128 LDS writes,
//      8-lanes-per-16B-slot (floor-optimal) on write and read.      32 KB
// Importance sum|x| stays fp32 per-thread (thread owns one px, all 256 ch)
// -> exact same top-40 semantics as v2, no LDS reduction needed.
// Layer 2: each px's 64 relu(H1) values live in lanes {l, l^16, l^32, l^48}
// (D-fragment rows 16mt+4g+r) -> dot with w2 in-register + 2x shfl_xor.
// ---------------------------------------------------------------------------
__global__ __launch_bounds__(256, 2) void k_mlp(
    const float* __restrict__ x,
    const float* __restrict__ w1, const float* __restrict__ b1,
    const float* __restrict__ w2, const float* __restrict__ b2,
    float* __restrict__ m, float* __restrict__ imp)
{
    __shared__ __align__(16) uint32_t WHu[64 * 128];   // fp16-pair W1 [hid][ch/2]
    __shared__ __align__(16) uint32_t XTu[256 * 32];   // fp16-pair X  [px][ch/2]

    const int t    = threadIdx.x;
    const int b    = blockIdx.x >> 4;            // 16 px-tiles per batch
    const int p0   = (blockIdx.x & 15) << 8;     // 256-px tile base
    const int lane = t & 63;
    const int wv   = t >> 6;                     // wave id: px quarter
    const int g    = lane >> 4;                  // k-group / D-row group
    const int lr   = lane & 15;                  // A-row / B-col / D-col

    // ---- stage W1 -> fp16 LDS once (coalesced float4 reads of 64 KB) ----
    #pragma unroll
    for (int i = 0; i < 16; ++i) {
        const int q   = t + (i << 8);            // float4 index in w1
        const int hid = q >> 6;
        const float4 wq = *(const float4*)(w1 + ((size_t)q << 2));
        half4_t hv;
        hv[0] = (_Float16)wq.x; hv[1] = (_Float16)wq.y;
        hv[2] = (_Float16)wq.z; hv[3] = (_Float16)wq.w;
        const int col = ((q & 63) * 2) ^ ((hid & 7) << 2);
        *reinterpret_cast<half4_t*>(&WHu[hid * 128 + col]) = hv;
    }

    // ---- accumulators seeded with b1 (C-in of first MFMA) ----
    f32x4_t acc[4][4];
    #pragma unroll
    for (int mt = 0; mt < 4; ++mt) {
        const float4 bv = *(const float4*)(b1 + mt * 16 + g * 4);
        #pragma unroll
        for (int nt = 0; nt < 4; ++nt) {
            acc[mt][nt][0] = bv.x; acc[mt][nt][1] = bv.y;
            acc[mt][nt][2] = bv.z; acc[mt][nt][3] = bv.w;
        }
    }

    float sa = 0.f;                               // fp32 sum|x| for this px
    const float* __restrict__ xb = x + ((size_t)b << 20) + p0 + t;

    for (int ck = 0; ck < 4; ++ck) {
        if (ck) __syncthreads();                  // protect XTu before overwrite
        // stage 64-ch chunk: thread t = px column p0+t, reads 64 dwords
        // (lane-consecutive px -> fully coalesced), cvt RTN -> fp16 pairs.
        const float* __restrict__ xc = xb + ((size_t)(ck * 64) << 12);
        #pragma unroll
        for (int jo = 0; jo < 8; ++jo) {
            float v[8];
            #pragma unroll
            for (int e = 0; e < 8; ++e) v[e] = xc[(size_t)(jo * 8 + e) << 12];
            half8_t hv;
            #pragma unroll
            for (int e = 0; e < 8; ++e) {
                hv[e] = (_Float16)v[e];
                sa += fabsf(v[e]);
            }
            const int col = (jo * 4) ^ ((t & 7) << 2);
            *reinterpret_cast<half8_t*>(&XTu[t * 32 + col]) = hv;
        }
        __syncthreads();
        // ---- 2 K-steps of 32: 16 MFMA each per wave ----
        #pragma unroll
        for (int k2 = 0; k2 < 2; ++k2) {
            const int ks = ck * 2 + k2;
            half8_t af[4], bf[4];
            #pragma unroll
            for (int mt = 0; mt < 4; ++mt) {      // A: W1[16mt+lr][32ks+8g..+7]
                const int hid = mt * 16 + lr;
                const int col = (ks * 16 + g * 4) ^ ((hid & 7) << 2);
                af[mt] = *reinterpret_cast<const half8_t*>(&WHu[hid * 128 + col]);
            }
            #pragma unroll
            for (int nt = 0; nt < 4; ++nt) {      // B: X[32k+8g..+7][px]
                const int px = wv * 64 + nt * 16 + lr;
                const int col = (k2 * 16 + g * 4) ^ ((px & 7) << 2);
                bf[nt] = *reinterpret_cast<const half8_t*>(&XTu[px * 32 + col]);
            }
            #pragma unroll
            for (int mt = 0; mt < 4; ++mt)
                #pragma unroll
                for (int nt = 0; nt < 4; ++nt)
                    acc[mt][nt] = __builtin_amdgcn_mfma_f32_16x16x32_f16(
                        af[mt], bf[nt], acc[mt][nt], 0, 0, 0);
        }
    }

    imp[((size_t)b << 12) + p0 + t] = sa;

    // ---- layer 2 (64 -> 4 heads) + sigmoid, fully in-register ----
    // lane holds relu(H1[hid][px]) for hid = 16mt + 4g + r, px = 64wv+16nt+lr
    float4 w2r[4][4];
    #pragma unroll
    for (int hd = 0; hd < 4; ++hd)
        #pragma unroll
        for (int mt = 0; mt < 4; ++mt)
            w2r[hd][mt] = *(const float4*)(w2 + hd * 64 + mt * 16 + g * 4);

    #pragma unroll
    for (int nt = 0; nt < 4; ++nt) {
        float s[4] = {0.f, 0.f, 0.f, 0.f};
        #pragma unroll
        for (int mt = 0; mt < 4; ++mt) {
            const float h0 = fmaxf(acc[mt][nt][0], 0.f);
            const float h1 = fmaxf(acc[mt][nt][1], 0.f);
            const float h2 = fmaxf(acc[mt][nt][2], 0.f);
            const float h3 = fmaxf(acc[mt][nt][3], 0.f);
            #pragma unroll
            for (int hd = 0; hd < 4; ++hd) {
                s[hd] = fmaf(w2r[hd][mt].x, h0, s[hd]);
                s[hd] = fmaf(w2r[hd][mt].y, h1, s[hd]);
                s[hd] = fmaf(w2r[hd][mt].z, h2, s[hd]);
                s[hd] = fmaf(w2r[hd][mt].w, h3, s[hd]);
            }
        }
        #pragma unroll
        for (int hd = 0; hd < 4; ++hd) {          // combine the 4 g-lanes
            s[hd] += __shfl_xor(s[hd], 16, 64);
            s[hd] += __shfl_xor(s[hd], 32, 64);
        }
        if (g == 0) {
            const float ssum =
                  1.f / (1.f + __expf(-(s[0] + b2[0])))
                + 1.f / (1.f + __expf(-(s[1] + b2[1])))
                + 1.f / (1.f + __expf(-(s[2] + b2[2])))
                + 1.f / (1.f + __expf(-(s[3] + b2[3])));
            m[((size_t)b << 12) + p0 + wv * 64 + nt * 16 + lr] = 0.175f * ssum;
        }
    }
}

// ---------------------------------------------------------------------------
// K2: per-batch top-40 extraction; winners get m += 0.3/40. (unchanged)
// ---------------------------------------------------------------------------
__global__ __launch_bounds__(64) void k_topk(
    const float* __restrict__ imp, float* __restrict__ m)
{
    const int b    = blockIdx.x;
    const int lane = threadIdx.x;
    const float* __restrict__ ib = imp + (size_t)b * HW_;
    float* __restrict__ mb = m + (size_t)b * HW_;

    float v[64];
    #pragma unroll
    for (int i = 0; i < 64; ++i) v[i] = ib[i * 64 + lane];

    float g[8];
    #pragma unroll
    for (int k = 0; k < 8; ++k) {
        float gm = v[8 * k];
        #pragma unroll
        for (int i = 1; i < 8; ++i) gm = fmaxf(gm, v[8 * k + i]);
        g[k] = gm;
    }

    for (int it = 0; it < SSEL_; ++it) {
        float lm = g[0];
        #pragma unroll
        for (int k = 1; k < 8; ++k) lm = fmaxf(lm, g[k]);
        float wm = lm;
        #pragma unroll
        for (int off = 32; off >= 1; off >>= 1)
            wm = fmaxf(wm, __shfl_xor(wm, off, 64));
        #pragma unroll
        for (int k = 0; k < 8; ++k) {
            if (__any(g[k] == wm)) {
                int gi = -1;
                #pragma unroll
                for (int i = 0; i < 8; ++i) {
                    if (v[8 * k + i] == wm) {
                        gi = (8 * k + i) * 64 + lane;
                        v[8 * k + i] = -FLT_MAX;
                    }
                }
                float gm = v[8 * k];
                #pragma unroll
                for (int i = 1; i < 8; ++i) gm = fmaxf(gm, v[8 * k + i]);
                g[k] = gm;
                if (gi >= 0) mb[gi] += GADD_;
            }
        }
    }
}

// ---------------------------------------------------------------------------
// K3: out[b,c,p] = x[b,c,p] * m[b,p]   (float4; m plane L2/L3-resident)
// ---------------------------------------------------------------------------
__global__ __launch_bounds__(256) void k_apply(
    const float4* __restrict__ x4, const float* __restrict__ m,
    float4* __restrict__ o4)
{
    const size_t i = (size_t)blockIdx.x * 256 + threadIdx.x;
    const size_t flat = i << 2;
    const int b = (int)(flat >> 20);          // C_*HW_ = 2^20
    const int p = (int)(flat & (HW_ - 1));
    const float4 mv = *(const float4*)(m + ((size_t)b << 12) + p);
    const float4 xv = x4[i];
    float4 r;
    r.x = xv.x * mv.x; r.y = xv.y * mv.y;
    r.z = xv.z * mv.z; r.w = xv.w * mv.w;
    o4[i] = r;
}

extern "C" void kernel_launch(void* const* d_in, const int* in_sizes, int n_in,
                              void* d_out, int out_size, void* d_ws, size_t ws_size,
                              hipStream_t stream)
{
    const float* x  = (const float*)d_in[0];
    const float* w1 = (const float*)d_in[1];  // gm_w1 [64,256]
    const float* b1 = (const float*)d_in[2];  // gm_b1 [64]
    const float* w2 = (const float*)d_in[3];  // gm_w2 [4,64]
    const float* b2 = (const float*)d_in[4];  // gm_b2 [4]
    // d_in[5..9] (qkv_w, ge_*) provably do not affect the output: softmax rows
    // mean to 1/S regardless of scores, so pixel_imp == 1/40 exactly.

    float* m   = (float*)d_ws;                 // B*HW floats (512 KB)
    float* imp = m + (size_t)B_ * HW_;         // B*HW floats (512 KB)
    float* out = (float*)d_out;

    k_mlp<<<dim3(B_ * (HW_ / 256)), dim3(256), 0, stream>>>(x, w1, b1, w2, b2, m, imp);
    k_topk<<<dim3(B_), dim3(64), 0, stream>>>(imp, m);
    const int n4 = (B_ * C_ * HW_) / 4;
    k_apply<<<dim3(n4 / 256), dim3(256), 0, stream>>>((const float4*)x, m, (float4*)out);
}